// Round 11
// baseline (679.012 us; speedup 1.0000x reference)
//
#include <hip/hip_runtime.h>

#define D 128
#define NNODES 100000
#define NEDGES 1600000
#define BN_EPS 1e-5f
#define NB_STATS 2048
#define NBLK_P 391   // ceil(NNODES/256)
#define NTILES 1563  // ceil(NNODES/64)
#define EPB    3125  // NEDGES / 512 gemm blocks, exact

// Scratch layout, offsets in float slots RELATIVE to scratch base `sb`.
// sb = d_ws when ws_size is large enough, else the E_X region of d_out
// (tail copy overwrites scratch last; ordering identical either way).
#define OFF_AX16   0          // 12.8M bf16 = 6.4M slots
#define OFF_BX16   6400000    // 12.8M bf16 = 6.4M slots
#define OFF_H16    12800000   // 12.8M bf16 = 6.4M slots (Hpre)
#define OFF_ESRC   19200000   // 1.6M int
#define OFF_ORDER  20800000   // 1.6M int
#define OFF_INDEG  22400000   // 100k int
#define OFF_LEXC   22510000   // 100k int
#define OFF_BPART  22620000   // 512 int
#define OFF_BSCAN  22621000   // 512 int
#define OFF_PSUM   22622000   // 2048*128 f32
#define OFF_PSQ    22900000   // 2048*128 f32
#define OFF_SCALE  23200000   // 128
#define OFF_SHIFT  23200128   // 128
#define WS_NEED_BYTES 92900000ull

#define MAIN_GEMM 512
#define MAIN_EDGE 2048
#define MAIN_AGG  2048
#define MAIN_FIN  2048

typedef __attribute__((ext_vector_type(8))) short bf16x8;
typedef __attribute__((ext_vector_type(4))) float f32x4;

static __device__ __forceinline__ unsigned short f2bf(float f) {
    unsigned int u = __float_as_uint(f);
    u = (u + 0x7FFF + ((u >> 16) & 1)) >> 16;   // RNE, finite data
    return (unsigned short)u;
}
static __device__ __forceinline__ float bf_lo(unsigned v) {
    return __uint_as_float(v << 16);
}
static __device__ __forceinline__ float bf_hi(unsigned v) {
    return __uint_as_float(v & 0xFFFF0000u);
}
static __device__ __forceinline__ bf16x8 pack8(float4 a, float4 b) {
    union { uint4 u; bf16x8 v; } r;
    r.u.x = (unsigned)f2bf(a.x) | ((unsigned)f2bf(a.y) << 16);
    r.u.y = (unsigned)f2bf(a.z) | ((unsigned)f2bf(a.w) << 16);
    r.u.z = (unsigned)f2bf(b.x) | ((unsigned)f2bf(b.y) << 16);
    r.u.w = (unsigned)f2bf(b.z) | ((unsigned)f2bf(b.w) << 16);
    return r.v;
}
static __device__ __forceinline__ uint2 packu2(float a0, float a1,
                                               float a2, float a3) {
    uint2 r;
    r.x = (unsigned)f2bf(a0) | ((unsigned)f2bf(a1) << 16);
    r.y = (unsigned)f2bf(a2) | ((unsigned)f2bf(a3) << 16);
    return r;
}

// ---------------------------------------------------------------------------
// MFMA GEMM + fused edge histogram.
// 320 threads = 5 waves. Waves 0-3: Y[i,d] = X[i,:]·W[d,:] + bias[d],
// wave = (matrix<<1)|colhalf, 64-row tile per iter, bf16 outputs.
// Wave 4: hist for this block's edge slice (order[e]=indeg[dst[e]]++),
// chunked between the tile barriers (atomic pipe overlaps matrix pipe).
// ---------------------------------------------------------------------------
__global__ __launch_bounds__(320, 2) void gemm2_kernel(
    const float* __restrict__ X,
    const float* __restrict__ Aw, const float* __restrict__ Ab,
    const float* __restrict__ Bw, const float* __restrict__ Bb,
    unsigned short* __restrict__ AX16, unsigned short* __restrict__ BX16,
    const int* __restrict__ dst, int* __restrict__ indeg,
    int* __restrict__ order)
{
    __shared__ unsigned short Xs[64][136];   // 272B row stride, 2-way free

    const int w    = threadIdx.x >> 6;   // wave 0..4
    const int lane = threadIdx.x & 63;
    const bool isB = (w >> 1) & 1;
    const int colbase = (w & 1) * 64;
    const int bn   = lane & 15;          // col-in-tile / row-in-tile
    const int kg   = lane >> 4;          // k-group 0..3 (8 k each)

    // hist slice for wave 4
    int       enext = blockIdx.x * EPB;
    const int eend  = enext + EPB;

    bf16x8 wf[4][4];
    float bias4[4];
    unsigned short* __restrict__ Y = isB ? BX16 : AX16;
    if (w < 4) {
        const float* __restrict__ Wm   = isB ? Bw : Aw;
        const float* __restrict__ bias = isB ? Bb : Ab;
#pragma unroll
        for (int ks = 0; ks < 4; ++ks)
#pragma unroll
            for (int ct = 0; ct < 4; ++ct) {
                const int d = colbase + ct * 16 + bn;
                const int k = ks * 32 + kg * 8;
                const float4* wp = (const float4*)&Wm[d * D + k];
                wf[ks][ct] = pack8(wp[0], wp[1]);
            }
#pragma unroll
        for (int ct = 0; ct < 4; ++ct)
            bias4[ct] = bias[colbase + ct * 16 + bn];
    }

    for (int t = blockIdx.x; t < NTILES; t += MAIN_GEMM) {
        const int row0 = t * 64;
        if (w < 4) {
            for (int c = threadIdx.x; c < 1024; c += 256) {
                const int r   = c >> 4;
                const int col = (c & 15) * 8;
                const int row = min(row0 + r, NNODES - 1);
                const float4* xp = (const float4*)&X[(size_t)row * D + col];
                const float4 x0 = xp[0], x1 = xp[1];
                uint4 pk;
                pk.x = (unsigned)f2bf(x0.x) | ((unsigned)f2bf(x0.y) << 16);
                pk.y = (unsigned)f2bf(x0.z) | ((unsigned)f2bf(x0.w) << 16);
                pk.z = (unsigned)f2bf(x1.x) | ((unsigned)f2bf(x1.y) << 16);
                pk.w = (unsigned)f2bf(x1.z) | ((unsigned)f2bf(x1.w) << 16);
                *(uint4*)&Xs[r][col] = pk;
            }
        }
        __syncthreads();

        if (w < 4) {
            f32x4 acc[4][4];   // [rowtile][coltile]
#pragma unroll
            for (int rt = 0; rt < 4; ++rt)
#pragma unroll
                for (int ct = 0; ct < 4; ++ct)
                    acc[rt][ct] = (f32x4){0.f, 0.f, 0.f, 0.f};

#pragma unroll
            for (int ks = 0; ks < 4; ++ks) {
                bf16x8 a[4];
#pragma unroll
                for (int rt = 0; rt < 4; ++rt)
                    a[rt] = *(const bf16x8*)
                        &Xs[rt * 16 + bn][ks * 32 + kg * 8];
#pragma unroll
                for (int rt = 0; rt < 4; ++rt)
#pragma unroll
                    for (int ct = 0; ct < 4; ++ct)
                        acc[rt][ct] =
                            __builtin_amdgcn_mfma_f32_16x16x32_bf16(
                                a[rt], wf[ks][ct], acc[rt][ct], 0, 0, 0);
            }
            __syncthreads();

            // epilogue: C row=(lane>>4)*4+r, col=lane&15 per 16x16
#pragma unroll
            for (int rt = 0; rt < 4; ++rt) {
#pragma unroll
                for (int r = 0; r < 4; ++r) {
                    const int row = row0 + rt * 16 + kg * 4 + r;
                    if (row < NNODES) {
                        unsigned short* yrow =
                            Y + (size_t)row * D + colbase;
#pragma unroll
                        for (int ct = 0; ct < 4; ++ct)
                            yrow[ct * 16 + bn] =
                                f2bf(acc[rt][ct][r] + bias4[ct]);
                    }
                }
            }
        } else {
            // wave 4: histogram chunk while waves 0-3 run MFMA
            const int lim = min(enext + 1024, eend);
            for (int idx = enext + lane; idx < lim; idx += 64) {
                const int dv = dst[idx];
                order[idx] = atomicAdd(&indeg[dv], 1);
            }
            enext = lim;
            __syncthreads();
        }
    }
    // drain remaining hist edges (no barriers past here)
    if (w == 4) {
        for (int idx = enext + lane; idx < eend; idx += 64) {
            const int dv = dst[idx];
            order[idx] = atomicAdd(&indeg[dv], 1);
        }
    }
}

// ---------------------------------------------------------------------------
// Scan: per-block exclusive scan + block totals; scan totals.
// row_start[i] computed on the fly later as bscan[i>>8] + lexc[i].
// ---------------------------------------------------------------------------
__global__ __launch_bounds__(256) void scan1_kernel(
    const int* __restrict__ indeg, int* __restrict__ lexc,
    int* __restrict__ bpart)
{
    __shared__ int ls[256];
    const int i = blockIdx.x * 256 + threadIdx.x;
    const int v = (i < NNODES) ? indeg[i] : 0;
    ls[threadIdx.x] = v;
    __syncthreads();
    for (int off = 1; off < 256; off <<= 1) {
        int u = (threadIdx.x >= off) ? ls[threadIdx.x - off] : 0;
        __syncthreads();
        ls[threadIdx.x] += u;
        __syncthreads();
    }
    if (i < NNODES) lexc[i] = ls[threadIdx.x] - v;
    if (threadIdx.x == 255) bpart[blockIdx.x] = ls[255];
}

__global__ __launch_bounds__(512) void scan2_kernel(
    const int* __restrict__ bpart, int* __restrict__ bscan)
{
    __shared__ int ls[512];
    const int t = threadIdx.x;
    const int v = (t < NBLK_P) ? bpart[t] : 0;
    ls[t] = v;
    __syncthreads();
    for (int off = 1; off < 512; off <<= 1) {
        int u = (t >= off) ? ls[t - off] : 0;
        __syncthreads();
        ls[t] += u;
        __syncthreads();
    }
    if (t < NBLK_P) bscan[t] = ls[t] - v;    // exclusive
}

// ---------------------------------------------------------------------------
// Fill CSR without atomics: esrc[bscan[v>>8] + lexc[v] + order[e]] = src[e].
// ---------------------------------------------------------------------------
__global__ __launch_bounds__(256) void fill_kernel(
    const int* __restrict__ src, const int* __restrict__ dst,
    const int* __restrict__ bscan, const int* __restrict__ lexc,
    const int* __restrict__ order, int* __restrict__ esrc)
{
    for (int e = blockIdx.x * 256 + threadIdx.x; e < NEDGES;
         e += MAIN_EDGE * 256) {
        const int v = dst[e];
        esrc[bscan[v >> 8] + lexc[v] + order[e]] = src[e];
    }
}

// ---------------------------------------------------------------------------
// Gather-aggregate + fused Hpre: HALF-WAVE per node.
// 32 lanes x uint2 (4 bf16 cols) per row; 2 nodes/wave; edge loop
// unrolled x8 -> 8 independent gather chains per half-wave (MLP).
// AX16 read bf16, Hpre written bf16.
// ---------------------------------------------------------------------------
__global__ __launch_bounds__(256, 8) void agg_kernel(
    const uint2* __restrict__ AX2, const uint2* __restrict__ BX2,
    const float4* __restrict__ X4, const float* __restrict__ snorm,
    const int* __restrict__ bscan, const int* __restrict__ lexc,
    const int* __restrict__ indeg, const int* __restrict__ esrc,
    uint2* __restrict__ H2, float* __restrict__ psum,
    float* __restrict__ psq)
{
    const int w    = threadIdx.x >> 6;   // wave in block, 0..3
    const int lane = threadIdx.x & 63;
    const int half = lane >> 5;          // 0..1: node slot
    const int hl   = lane & 31;          // lane within half-wave
    float s0=0.f,s1=0.f,s2=0.f,s3=0.f, q0=0.f,q1=0.f,q2=0.f,q3=0.f;

    const int wid = blockIdx.x * 4 + w;  // 0..8191
    for (int base = wid * 2; base < NNODES; base += MAIN_AGG * 8) {
        const int i = base + half;
        if (i < NNODES) {
            float a0, a1, a2, a3;
            const int deg = indeg[i];
            if (deg > 0) {
                const int rs = bscan[i >> 8] + lexc[i];
                const uint2 av = AX2[(size_t)i * 32 + hl];
                a0 = bf_lo(av.x); a1 = bf_hi(av.x);
                a2 = bf_lo(av.y); a3 = bf_hi(av.y);
                int e = rs;
                const int re = rs + deg;
                for (; e + 8 <= re; e += 8) {
                    const int i0 = esrc[e + 0], i1 = esrc[e + 1];
                    const int i2 = esrc[e + 2], i3 = esrc[e + 3];
                    const int i4 = esrc[e + 4], i5 = esrc[e + 5];
                    const int i6 = esrc[e + 6], i7 = esrc[e + 7];
                    const uint2 v0 = BX2[(size_t)i0 * 32 + hl];
                    const uint2 v1 = BX2[(size_t)i1 * 32 + hl];
                    const uint2 v2 = BX2[(size_t)i2 * 32 + hl];
                    const uint2 v3 = BX2[(size_t)i3 * 32 + hl];
                    const uint2 v4 = BX2[(size_t)i4 * 32 + hl];
                    const uint2 v5 = BX2[(size_t)i5 * 32 + hl];
                    const uint2 v6 = BX2[(size_t)i6 * 32 + hl];
                    const uint2 v7 = BX2[(size_t)i7 * 32 + hl];
                    a0 += bf_lo(v0.x)+bf_lo(v1.x)+bf_lo(v2.x)+bf_lo(v3.x)
                        + bf_lo(v4.x)+bf_lo(v5.x)+bf_lo(v6.x)+bf_lo(v7.x);
                    a1 += bf_hi(v0.x)+bf_hi(v1.x)+bf_hi(v2.x)+bf_hi(v3.x)
                        + bf_hi(v4.x)+bf_hi(v5.x)+bf_hi(v6.x)+bf_hi(v7.x);
                    a2 += bf_lo(v0.y)+bf_lo(v1.y)+bf_lo(v2.y)+bf_lo(v3.y)
                        + bf_lo(v4.y)+bf_lo(v5.y)+bf_lo(v6.y)+bf_lo(v7.y);
                    a3 += bf_hi(v0.y)+bf_hi(v1.y)+bf_hi(v2.y)+bf_hi(v3.y)
                        + bf_hi(v4.y)+bf_hi(v5.y)+bf_hi(v6.y)+bf_hi(v7.y);
                }
                for (; e + 4 <= re; e += 4) {
                    const int i0 = esrc[e + 0], i1 = esrc[e + 1];
                    const int i2 = esrc[e + 2], i3 = esrc[e + 3];
                    const uint2 v0 = BX2[(size_t)i0 * 32 + hl];
                    const uint2 v1 = BX2[(size_t)i1 * 32 + hl];
                    const uint2 v2 = BX2[(size_t)i2 * 32 + hl];
                    const uint2 v3 = BX2[(size_t)i3 * 32 + hl];
                    a0 += bf_lo(v0.x)+bf_lo(v1.x)+bf_lo(v2.x)+bf_lo(v3.x);
                    a1 += bf_hi(v0.x)+bf_hi(v1.x)+bf_hi(v2.x)+bf_hi(v3.x);
                    a2 += bf_lo(v0.y)+bf_lo(v1.y)+bf_lo(v2.y)+bf_lo(v3.y);
                    a3 += bf_hi(v0.y)+bf_hi(v1.y)+bf_hi(v2.y)+bf_hi(v3.y);
                }
                for (; e < re; ++e) {
                    const uint2 v = BX2[(size_t)esrc[e] * 32 + hl];
                    a0 += bf_lo(v.x); a1 += bf_hi(v.x);
                    a2 += bf_lo(v.y); a3 += bf_hi(v.y);
                }
            } else {
                float4 x = X4[(size_t)i * 32 + hl];
                a0 = x.x; a1 = x.y; a2 = x.z; a3 = x.w;
            }
            const float sn = snorm[i];
            a0 *= sn; a1 *= sn; a2 *= sn; a3 *= sn;
            H2[(size_t)i * 32 + hl] = packu2(a0, a1, a2, a3);
            s0 += a0; s1 += a1; s2 += a2; s3 += a3;
            q0 += a0*a0; q1 += a1*a1; q2 += a2*a2; q3 += a3*a3;
        }
    }

    __shared__ float sp[4][64][4], sq[4][64][4];
    sp[w][lane][0]=s0; sp[w][lane][1]=s1; sp[w][lane][2]=s2; sp[w][lane][3]=s3;
    sq[w][lane][0]=q0; sq[w][lane][1]=q1; sq[w][lane][2]=q2; sq[w][lane][3]=q3;
    __syncthreads();
    if (threadIdx.x < D) {
        const int c  = threadIdx.x;
        const int l0 = c >> 2;       // owning hl
        const int j  = c & 3;
        float S = 0.f, Q = 0.f;
#pragma unroll
        for (int w2 = 0; w2 < 4; ++w2) {
            S += sp[w2][l0][j] + sp[w2][32 + l0][j];
            Q += sq[w2][l0][j] + sq[w2][32 + l0][j];
        }
        psum[blockIdx.x * D + c] = S;
        psq [blockIdx.x * D + c] = Q;
    }
}

// ---------------------------------------------------------------------------
// Reduce partials -> scale/shift for fused BN.
// ---------------------------------------------------------------------------
__global__ __launch_bounds__(1024) void bnstats_kernel(
    const float* __restrict__ psum, const float* __restrict__ psq,
    const float* __restrict__ gamma, const float* __restrict__ beta,
    float* __restrict__ scale, float* __restrict__ shift)
{
    const int c = threadIdx.x & 127;
    const int g = threadIdx.x >> 7;   // 0..7
    float s = 0.f, q = 0.f;
    for (int b = g; b < NB_STATS; b += 8) {
        s += psum[b * D + c];
        q += psq [b * D + c];
    }
    __shared__ float ls[8][D], lq[8][D];
    ls[g][c] = s;
    lq[g][c] = q;
    __syncthreads();
    if (threadIdx.x < D) {
        float S = 0.f, Q = 0.f;
#pragma unroll
        for (int g2 = 0; g2 < 8; ++g2) { S += ls[g2][c]; Q += lq[g2][c]; }
        const float inv_n = 1.0f / (float)NNODES;
        float mean = S * inv_n;
        float var  = Q * inv_n - mean * mean;
        float sc   = rsqrtf(var + BN_EPS) * gamma[c];
        scale[c] = sc;
        shift[c] = beta[c] - mean * sc;
    }
}

// ---------------------------------------------------------------------------
// out = X + relu(Hpre * scale + shift); Hpre is bf16 (uint2 = 4 cols).
// ---------------------------------------------------------------------------
__global__ __launch_bounds__(256) void final_kernel(
    const uint2* __restrict__ H2, const float* __restrict__ X,
    const float* __restrict__ scale, const float* __restrict__ shift,
    float* __restrict__ out)
{
    const int total = NNODES * D / 4;
    for (int i = blockIdx.x * 256 + threadIdx.x; i < total;
         i += MAIN_FIN * 256) {
        const uint2 hv = H2[i];
        float4 x = ((const float4*)X)[i];
        int d0 = (i * 4) & 127;
        float4 r;
        r.x = x.x + fmaxf(0.f, bf_lo(hv.x) * scale[d0 + 0] + shift[d0 + 0]);
        r.y = x.y + fmaxf(0.f, bf_hi(hv.x) * scale[d0 + 1] + shift[d0 + 1]);
        r.z = x.z + fmaxf(0.f, bf_lo(hv.y) * scale[d0 + 2] + shift[d0 + 2]);
        r.w = x.w + fmaxf(0.f, bf_hi(hv.y) * scale[d0 + 3] + shift[d0 + 3]);
        ((float4*)out)[i] = r;
    }
}

extern "C" void kernel_launch(void* const* d_in, const int* in_sizes, int n_in,
                              void* d_out, int out_size, void* d_ws, size_t ws_size,
                              hipStream_t stream)
{
    const float* X       = (const float*)d_in[0];
    const float* E_X     = (const float*)d_in[1];
    const float* snorm_n = (const float*)d_in[2];
    const int*   src     = (const int*)d_in[4];
    const int*   dst     = (const int*)d_in[5];
    const float* A_w     = (const float*)d_in[6];
    const float* A_b     = (const float*)d_in[7];
    const float* B_w     = (const float*)d_in[8];
    const float* B_b     = (const float*)d_in[9];
    const float* gamma   = (const float*)d_in[10];
    const float* beta    = (const float*)d_in[11];

    float* out = (float*)d_out;
    const bool use_ws = (ws_size >= WS_NEED_BYTES);
    float* sb = use_ws ? (float*)d_ws : (out + (size_t)NNODES * D);

    unsigned short* AX16  = (unsigned short*)(sb + OFF_AX16);
    unsigned short* BX16  = (unsigned short*)(sb + OFF_BX16);
    unsigned short* H16   = (unsigned short*)(sb + OFF_H16);
    int*            esrc  = (int*)(sb + OFF_ESRC);
    int*            order = (int*)(sb + OFF_ORDER);
    int*            indeg = (int*)(sb + OFF_INDEG);
    int*            lexc  = (int*)(sb + OFF_LEXC);
    int*            bpart = (int*)(sb + OFF_BPART);
    int*            bscan = (int*)(sb + OFF_BSCAN);
    float*          psum  = sb + OFF_PSUM;
    float*          psq   = sb + OFF_PSQ;
    float*          scale = sb + OFF_SCALE;
    float*          shift = sb + OFF_SHIFT;

    hipMemsetAsync(indeg, 0, NNODES * sizeof(int), stream);

    gemm2_kernel<<<MAIN_GEMM, 320, 0, stream>>>(
        X, A_w, A_b, B_w, B_b, AX16, BX16, dst, indeg, order);
    scan1_kernel<<<NBLK_P, 256, 0, stream>>>(indeg, lexc, bpart);
    scan2_kernel<<<1, 512, 0, stream>>>(bpart, bscan);
    fill_kernel<<<MAIN_EDGE, 256, 0, stream>>>(
        src, dst, bscan, lexc, order, esrc);
    agg_kernel<<<MAIN_AGG, 256, 0, stream>>>(
        (const uint2*)AX16, (const uint2*)BX16, (const float4*)X, snorm_n,
        bscan, lexc, indeg, esrc, (uint2*)H16, psum, psq);
    bnstats_kernel<<<1, 1024, 0, stream>>>(psum, psq, gamma, beta,
                                           scale, shift);
    final_kernel<<<MAIN_FIN, 256, 0, stream>>>(
        (const uint2*)H16, X, scale, shift, out);

    // E_X passthrough tail (runtime blit).
    hipMemcpyAsync(out + (size_t)NNODES * D, E_X,
                   (size_t)NEDGES * D * sizeof(float),
                   hipMemcpyDeviceToDevice, stream);
}

// Round 12
// 637.353 us; speedup vs baseline: 1.0654x; 1.0654x over previous
//
#include <hip/hip_runtime.h>

#define D 128
#define NNODES 100000
#define NEDGES 1600000
#define BN_EPS 1e-5f
#define NB_STATS 2048
#define NBLK_P 391   // ceil(NNODES/256)
#define NTILES 1563  // ceil(NNODES/64)

// Scratch layout, offsets in float slots RELATIVE to scratch base `sb`.
// sb = d_ws when ws_size is large enough, else the E_X region of d_out
// (tail copy overwrites scratch last; ordering identical either way).
#define OFF_AX16   0          // 12.8M bf16 = 6.4M slots
#define OFF_BX16   6400000    // 12.8M bf16 = 6.4M slots
#define OFF_H16    12800000   // 12.8M bf16 = 6.4M slots (Hpre)
#define OFF_ESRC   19200000   // 1.6M int
#define OFF_ORDER  20800000   // 1.6M int
#define OFF_INDEG  22400000   // 100k int
#define OFF_LEXC   22510000   // 100k int
#define OFF_BPART  22620000   // 512 int
#define OFF_BSCAN  22621000   // 512 int
#define OFF_PSUM   22622000   // 2048*128 f32
#define OFF_PSQ    22900000   // 2048*128 f32
#define OFF_SCALE  23200000   // 128
#define OFF_SHIFT  23200128   // 128
#define WS_NEED_BYTES 92900000ull

#define MAIN_GEMM 512
#define MAIN_EDGE 2048
#define MAIN_AGG  2048
#define MAIN_FIN  2048

typedef __attribute__((ext_vector_type(8))) short bf16x8;
typedef __attribute__((ext_vector_type(4))) float f32x4;

static __device__ __forceinline__ unsigned short f2bf(float f) {
    unsigned int u = __float_as_uint(f);
    u = (u + 0x7FFF + ((u >> 16) & 1)) >> 16;   // RNE, finite data
    return (unsigned short)u;
}
static __device__ __forceinline__ float bf_lo(unsigned v) {
    return __uint_as_float(v << 16);
}
static __device__ __forceinline__ float bf_hi(unsigned v) {
    return __uint_as_float(v & 0xFFFF0000u);
}
static __device__ __forceinline__ bf16x8 pack8(float4 a, float4 b) {
    union { uint4 u; bf16x8 v; } r;
    r.u.x = (unsigned)f2bf(a.x) | ((unsigned)f2bf(a.y) << 16);
    r.u.y = (unsigned)f2bf(a.z) | ((unsigned)f2bf(a.w) << 16);
    r.u.z = (unsigned)f2bf(b.x) | ((unsigned)f2bf(b.y) << 16);
    r.u.w = (unsigned)f2bf(b.z) | ((unsigned)f2bf(b.w) << 16);
    return r.v;
}
static __device__ __forceinline__ uint2 packu2(float a0, float a1,
                                               float a2, float a3) {
    uint2 r;
    r.x = (unsigned)f2bf(a0) | ((unsigned)f2bf(a1) << 16);
    r.y = (unsigned)f2bf(a2) | ((unsigned)f2bf(a3) << 16);
    return r;
}

// ---------------------------------------------------------------------------
// MFMA GEMM: Y[i,d] = sum_k X[i,k] * W[d,k] + bias[d], both A and B.
// 64-row tile per block iter; 4 waves: wave = (matrix<<1)|colhalf.
// Both outputs stored bf16.
// ---------------------------------------------------------------------------
__global__ __launch_bounds__(256, 2) void gemm2_kernel(
    const float* __restrict__ X,
    const float* __restrict__ Aw, const float* __restrict__ Ab,
    const float* __restrict__ Bw, const float* __restrict__ Bb,
    unsigned short* __restrict__ AX16, unsigned short* __restrict__ BX16)
{
    __shared__ unsigned short Xs[64][136];   // 272B row stride, 2-way free

    const int w    = threadIdx.x >> 6;   // wave 0..3
    const int lane = threadIdx.x & 63;
    const bool isB = (w >> 1);
    const int colbase = (w & 1) * 64;
    const int bn   = lane & 15;          // col-in-tile / row-in-tile
    const int kg   = lane >> 4;          // k-group 0..3 (8 k each)

    const float* __restrict__ Wm   = isB ? Bw : Aw;
    const float* __restrict__ bias = isB ? Bb : Ab;
    unsigned short* __restrict__ Y = isB ? BX16 : AX16;

    bf16x8 wf[4][4];
#pragma unroll
    for (int ks = 0; ks < 4; ++ks)
#pragma unroll
        for (int ct = 0; ct < 4; ++ct) {
            const int d = colbase + ct * 16 + bn;
            const int k = ks * 32 + kg * 8;
            const float4* wp = (const float4*)&Wm[d * D + k];
            wf[ks][ct] = pack8(wp[0], wp[1]);
        }

    float bias4[4];
#pragma unroll
    for (int ct = 0; ct < 4; ++ct) bias4[ct] = bias[colbase + ct * 16 + bn];

    for (int t = blockIdx.x; t < NTILES; t += MAIN_GEMM) {
        const int row0 = t * 64;
        for (int c = threadIdx.x; c < 1024; c += 256) {
            const int r   = c >> 4;
            const int col = (c & 15) * 8;
            const int row = min(row0 + r, NNODES - 1);
            const float4* xp = (const float4*)&X[(size_t)row * D + col];
            const float4 x0 = xp[0], x1 = xp[1];
            uint4 pk;
            pk.x = (unsigned)f2bf(x0.x) | ((unsigned)f2bf(x0.y) << 16);
            pk.y = (unsigned)f2bf(x0.z) | ((unsigned)f2bf(x0.w) << 16);
            pk.z = (unsigned)f2bf(x1.x) | ((unsigned)f2bf(x1.y) << 16);
            pk.w = (unsigned)f2bf(x1.z) | ((unsigned)f2bf(x1.w) << 16);
            *(uint4*)&Xs[r][col] = pk;
        }
        __syncthreads();

        f32x4 acc[4][4];   // [rowtile][coltile]
#pragma unroll
        for (int rt = 0; rt < 4; ++rt)
#pragma unroll
            for (int ct = 0; ct < 4; ++ct)
                acc[rt][ct] = (f32x4){0.f, 0.f, 0.f, 0.f};

#pragma unroll
        for (int ks = 0; ks < 4; ++ks) {
            bf16x8 a[4];
#pragma unroll
            for (int rt = 0; rt < 4; ++rt)
                a[rt] = *(const bf16x8*)&Xs[rt * 16 + bn][ks * 32 + kg * 8];
#pragma unroll
            for (int rt = 0; rt < 4; ++rt)
#pragma unroll
                for (int ct = 0; ct < 4; ++ct)
                    acc[rt][ct] = __builtin_amdgcn_mfma_f32_16x16x32_bf16(
                        a[rt], wf[ks][ct], acc[rt][ct], 0, 0, 0);
        }
        __syncthreads();

        // epilogue: C row=(lane>>4)*4+r, col=lane&15 within each 16x16
#pragma unroll
        for (int rt = 0; rt < 4; ++rt) {
#pragma unroll
            for (int r = 0; r < 4; ++r) {
                const int row = row0 + rt * 16 + kg * 4 + r;
                if (row < NNODES) {
                    unsigned short* yrow = Y + (size_t)row * D + colbase;
#pragma unroll
                    for (int ct = 0; ct < 4; ++ct)
                        yrow[ct * 16 + bn] = f2bf(acc[rt][ct][r] + bias4[ct]);
                }
            }
        }
    }
}

// ---------------------------------------------------------------------------
// Histogram + per-edge rank: order[e] = indeg[dst[e]]++ (int atomics).
// ---------------------------------------------------------------------------
__global__ __launch_bounds__(256) void hist_kernel(
    const int* __restrict__ dst, int* __restrict__ indeg,
    int* __restrict__ order)
{
    for (int e = blockIdx.x * 256 + threadIdx.x; e < NEDGES;
         e += MAIN_EDGE * 256)
        order[e] = atomicAdd(&indeg[dst[e]], 1);
}

// ---------------------------------------------------------------------------
// Scan: per-block exclusive scan + block totals; scan totals.
// row_start[i] computed on the fly later as bscan[i>>8] + lexc[i].
// ---------------------------------------------------------------------------
__global__ __launch_bounds__(256) void scan1_kernel(
    const int* __restrict__ indeg, int* __restrict__ lexc,
    int* __restrict__ bpart)
{
    __shared__ int ls[256];
    const int i = blockIdx.x * 256 + threadIdx.x;
    const int v = (i < NNODES) ? indeg[i] : 0;
    ls[threadIdx.x] = v;
    __syncthreads();
    for (int off = 1; off < 256; off <<= 1) {
        int u = (threadIdx.x >= off) ? ls[threadIdx.x - off] : 0;
        __syncthreads();
        ls[threadIdx.x] += u;
        __syncthreads();
    }
    if (i < NNODES) lexc[i] = ls[threadIdx.x] - v;
    if (threadIdx.x == 255) bpart[blockIdx.x] = ls[255];
}

__global__ __launch_bounds__(512) void scan2_kernel(
    const int* __restrict__ bpart, int* __restrict__ bscan)
{
    __shared__ int ls[512];
    const int t = threadIdx.x;
    const int v = (t < NBLK_P) ? bpart[t] : 0;
    ls[t] = v;
    __syncthreads();
    for (int off = 1; off < 512; off <<= 1) {
        int u = (t >= off) ? ls[t - off] : 0;
        __syncthreads();
        ls[t] += u;
        __syncthreads();
    }
    if (t < NBLK_P) bscan[t] = ls[t] - v;    // exclusive
}

// ---------------------------------------------------------------------------
// Fill CSR without atomics: esrc[bscan[v>>8] + lexc[v] + order[e]] = src[e].
// ---------------------------------------------------------------------------
__global__ __launch_bounds__(256) void fill_kernel(
    const int* __restrict__ src, const int* __restrict__ dst,
    const int* __restrict__ bscan, const int* __restrict__ lexc,
    const int* __restrict__ order, int* __restrict__ esrc)
{
    for (int e = blockIdx.x * 256 + threadIdx.x; e < NEDGES;
         e += MAIN_EDGE * 256) {
        const int v = dst[e];
        esrc[bscan[v >> 8] + lexc[v] + order[e]] = src[e];
    }
}

// ---------------------------------------------------------------------------
// Gather-aggregate + fused Hpre: HALF-WAVE per node.
// 32 lanes x uint2 (4 bf16 cols) per row; 2 nodes/wave; edge loop
// unrolled x4. AX16 read bf16, Hpre written bf16.
// ---------------------------------------------------------------------------
__global__ __launch_bounds__(256, 8) void agg_kernel(
    const uint2* __restrict__ AX2, const uint2* __restrict__ BX2,
    const float4* __restrict__ X4, const float* __restrict__ snorm,
    const int* __restrict__ bscan, const int* __restrict__ lexc,
    const int* __restrict__ indeg, const int* __restrict__ esrc,
    uint2* __restrict__ H2, float* __restrict__ psum,
    float* __restrict__ psq)
{
    const int w    = threadIdx.x >> 6;   // wave in block, 0..3
    const int lane = threadIdx.x & 63;
    const int half = lane >> 5;          // 0..1: node slot
    const int hl   = lane & 31;          // lane within half-wave
    float s0=0.f,s1=0.f,s2=0.f,s3=0.f, q0=0.f,q1=0.f,q2=0.f,q3=0.f;

    const int wid = blockIdx.x * 4 + w;  // 0..8191
    for (int base = wid * 2; base < NNODES; base += MAIN_AGG * 8) {
        const int i = base + half;
        if (i < NNODES) {
            float a0, a1, a2, a3;
            const int deg = indeg[i];
            if (deg > 0) {
                const int rs = bscan[i >> 8] + lexc[i];
                const uint2 av = AX2[(size_t)i * 32 + hl];
                a0 = bf_lo(av.x); a1 = bf_hi(av.x);
                a2 = bf_lo(av.y); a3 = bf_hi(av.y);
                int e = rs;
                const int re = rs + deg;
                for (; e + 4 <= re; e += 4) {
                    const uint2 v0 = BX2[(size_t)esrc[e + 0] * 32 + hl];
                    const uint2 v1 = BX2[(size_t)esrc[e + 1] * 32 + hl];
                    const uint2 v2 = BX2[(size_t)esrc[e + 2] * 32 + hl];
                    const uint2 v3 = BX2[(size_t)esrc[e + 3] * 32 + hl];
                    a0 += bf_lo(v0.x)+bf_lo(v1.x)+bf_lo(v2.x)+bf_lo(v3.x);
                    a1 += bf_hi(v0.x)+bf_hi(v1.x)+bf_hi(v2.x)+bf_hi(v3.x);
                    a2 += bf_lo(v0.y)+bf_lo(v1.y)+bf_lo(v2.y)+bf_lo(v3.y);
                    a3 += bf_hi(v0.y)+bf_hi(v1.y)+bf_hi(v2.y)+bf_hi(v3.y);
                }
                for (; e < re; ++e) {
                    const uint2 v = BX2[(size_t)esrc[e] * 32 + hl];
                    a0 += bf_lo(v.x); a1 += bf_hi(v.x);
                    a2 += bf_lo(v.y); a3 += bf_hi(v.y);
                }
            } else {
                float4 x = X4[(size_t)i * 32 + hl];
                a0 = x.x; a1 = x.y; a2 = x.z; a3 = x.w;
            }
            const float sn = snorm[i];
            a0 *= sn; a1 *= sn; a2 *= sn; a3 *= sn;
            H2[(size_t)i * 32 + hl] = packu2(a0, a1, a2, a3);
            s0 += a0; s1 += a1; s2 += a2; s3 += a3;
            q0 += a0*a0; q1 += a1*a1; q2 += a2*a2; q3 += a3*a3;
        }
    }

    __shared__ float sp[4][64][4], sq[4][64][4];
    sp[w][lane][0]=s0; sp[w][lane][1]=s1; sp[w][lane][2]=s2; sp[w][lane][3]=s3;
    sq[w][lane][0]=q0; sq[w][lane][1]=q1; sq[w][lane][2]=q2; sq[w][lane][3]=q3;
    __syncthreads();
    if (threadIdx.x < D) {
        const int c  = threadIdx.x;
        const int l0 = c >> 2;       // owning hl
        const int j  = c & 3;
        float S = 0.f, Q = 0.f;
#pragma unroll
        for (int w2 = 0; w2 < 4; ++w2) {
            S += sp[w2][l0][j] + sp[w2][32 + l0][j];
            Q += sq[w2][l0][j] + sq[w2][32 + l0][j];
        }
        psum[blockIdx.x * D + c] = S;
        psq [blockIdx.x * D + c] = Q;
    }
}

// ---------------------------------------------------------------------------
// Reduce partials -> scale/shift for fused BN.
// ---------------------------------------------------------------------------
__global__ __launch_bounds__(1024) void bnstats_kernel(
    const float* __restrict__ psum, const float* __restrict__ psq,
    const float* __restrict__ gamma, const float* __restrict__ beta,
    float* __restrict__ scale, float* __restrict__ shift)
{
    const int c = threadIdx.x & 127;
    const int g = threadIdx.x >> 7;   // 0..7
    float s = 0.f, q = 0.f;
    for (int b = g; b < NB_STATS; b += 8) {
        s += psum[b * D + c];
        q += psq [b * D + c];
    }
    __shared__ float ls[8][D], lq[8][D];
    ls[g][c] = s;
    lq[g][c] = q;
    __syncthreads();
    if (threadIdx.x < D) {
        float S = 0.f, Q = 0.f;
#pragma unroll
        for (int g2 = 0; g2 < 8; ++g2) { S += ls[g2][c]; Q += lq[g2][c]; }
        const float inv_n = 1.0f / (float)NNODES;
        float mean = S * inv_n;
        float var  = Q * inv_n - mean * mean;
        float sc   = rsqrtf(var + BN_EPS) * gamma[c];
        scale[c] = sc;
        shift[c] = beta[c] - mean * sc;
    }
}

// ---------------------------------------------------------------------------
// out = X + relu(Hpre * scale + shift); Hpre is bf16 (uint2 = 4 cols).
// ---------------------------------------------------------------------------
__global__ __launch_bounds__(256) void final_kernel(
    const uint2* __restrict__ H2, const float* __restrict__ X,
    const float* __restrict__ scale, const float* __restrict__ shift,
    float* __restrict__ out)
{
    const int total = NNODES * D / 4;
    for (int i = blockIdx.x * 256 + threadIdx.x; i < total;
         i += MAIN_FIN * 256) {
        const uint2 hv = H2[i];
        float4 x = ((const float4*)X)[i];
        int d0 = (i * 4) & 127;
        float4 r;
        r.x = x.x + fmaxf(0.f, bf_lo(hv.x) * scale[d0 + 0] + shift[d0 + 0]);
        r.y = x.y + fmaxf(0.f, bf_hi(hv.x) * scale[d0 + 1] + shift[d0 + 1]);
        r.z = x.z + fmaxf(0.f, bf_lo(hv.y) * scale[d0 + 2] + shift[d0 + 2]);
        r.w = x.w + fmaxf(0.f, bf_hi(hv.y) * scale[d0 + 3] + shift[d0 + 3]);
        ((float4*)out)[i] = r;
    }
}

extern "C" void kernel_launch(void* const* d_in, const int* in_sizes, int n_in,
                              void* d_out, int out_size, void* d_ws, size_t ws_size,
                              hipStream_t stream)
{
    const float* X       = (const float*)d_in[0];
    const float* E_X     = (const float*)d_in[1];
    const float* snorm_n = (const float*)d_in[2];
    const int*   src     = (const int*)d_in[4];
    const int*   dst     = (const int*)d_in[5];
    const float* A_w     = (const float*)d_in[6];
    const float* A_b     = (const float*)d_in[7];
    const float* B_w     = (const float*)d_in[8];
    const float* B_b     = (const float*)d_in[9];
    const float* gamma   = (const float*)d_in[10];
    const float* beta    = (const float*)d_in[11];

    float* out = (float*)d_out;
    const bool use_ws = (ws_size >= WS_NEED_BYTES);
    float* sb = use_ws ? (float*)d_ws : (out + (size_t)NNODES * D);

    unsigned short* AX16  = (unsigned short*)(sb + OFF_AX16);
    unsigned short* BX16  = (unsigned short*)(sb + OFF_BX16);
    unsigned short* H16   = (unsigned short*)(sb + OFF_H16);
    int*            esrc  = (int*)(sb + OFF_ESRC);
    int*            order = (int*)(sb + OFF_ORDER);
    int*            indeg = (int*)(sb + OFF_INDEG);
    int*            lexc  = (int*)(sb + OFF_LEXC);
    int*            bpart = (int*)(sb + OFF_BPART);
    int*            bscan = (int*)(sb + OFF_BSCAN);
    float*          psum  = sb + OFF_PSUM;
    float*          psq   = sb + OFF_PSQ;
    float*          scale = sb + OFF_SCALE;
    float*          shift = sb + OFF_SHIFT;

    hipMemsetAsync(indeg, 0, NNODES * sizeof(int), stream);

    gemm2_kernel<<<MAIN_GEMM, 256, 0, stream>>>(
        X, A_w, A_b, B_w, B_b, AX16, BX16);
    hist_kernel<<<MAIN_EDGE, 256, 0, stream>>>(dst, indeg, order);
    scan1_kernel<<<NBLK_P, 256, 0, stream>>>(indeg, lexc, bpart);
    scan2_kernel<<<1, 512, 0, stream>>>(bpart, bscan);
    fill_kernel<<<MAIN_EDGE, 256, 0, stream>>>(
        src, dst, bscan, lexc, order, esrc);
    agg_kernel<<<MAIN_AGG, 256, 0, stream>>>(
        (const uint2*)AX16, (const uint2*)BX16, (const float4*)X, snorm_n,
        bscan, lexc, indeg, esrc, (uint2*)H16, psum, psq);
    bnstats_kernel<<<1, 1024, 0, stream>>>(psum, psq, gamma, beta,
                                           scale, shift);
    final_kernel<<<MAIN_FIN, 256, 0, stream>>>(
        (const uint2*)H16, X, scale, shift, out);

    // E_X passthrough tail (runtime blit).
    hipMemcpyAsync(out + (size_t)NNODES * D, E_X,
                   (size_t)NEDGES * D * sizeof(float),
                   hipMemcpyDeviceToDevice, stream);
}